// Round 1
// baseline (73.471 us; speedup 1.0000x reference)
//
#include <hip/hip_runtime.h>
#include <hip/hip_fp16.h>
#include <math.h>

#define HW    4096
#define NC    32
#define NB    8
#define TINV  10.0f            // 1/TEMP
#define RWIN  8                // window radius; missed sources need |of|>5.5
#define WDIM  (8 + 2 * RWIN)   // 24
#define NSRC  (WDIM * WDIM)    // 576
#define RCUT  2.0f             // rect cut; error impact unmeasurable at R12

// Fully fused: per (tile, channel-half, batch) block recomputes the 24x24
// source-window params and stages the x window in LDS as half2. No workspace,
// no prep kernel, no global survivor gather on the critical path.

__device__ __forceinline__ __half2 u32_as_h2(unsigned int u) {
    union { unsigned int u; __half2 h; } c; c.u = u; return c.h;
}
__device__ __forceinline__ unsigned int h2_as_u32(__half2 h) {
    union { __half2 h; unsigned int u; } c; c.h = h; return c.u;
}

// grid: (64 tiles, 2 channel-halves, 8 batches); 16 channels per block
__global__ __launch_bounds__(256) void warp_fused_kernel(
    const float* __restrict__ x, const float* __restrict__ of,
    float* __restrict__ out)
{
    __shared__ float4       pw[NSRC];        // window params (9216 B); redu overlays after FMA
    __shared__ unsigned int xw[NSRC * 8];    // window x, half2 ch-pairs [src][8] (18432 B)
    __shared__ float4       wp[4][65];       // survivor params + dummy slot
    __shared__ int          sj[4][64];       // survivor window idx

    const int b    = blockIdx.z;
    const int h    = blockIdx.y;             // channel half
    const int tile = blockIdx.x;
    const int ty0  = (tile >> 3) << 3;
    const int tx0  = (tile & 7) << 3;
    const int tid  = threadIdx.x;
    const int lane = tid & 63;
    const int wv   = __builtin_amdgcn_readfirstlane(tid >> 6);

    // ---- stage 1: params for the 24x24 window (identical math to old prep) ----
    for (int s = tid; s < NSRC; s += 256) {
        int wr = s / WDIM, wc = s - wr * WDIM;
        int jy = ty0 - RWIN + wr, jx = tx0 - RWIN + wc;
        float4 pv = make_float4(0.f, 0.f, 0.f, 0.f);
        if (((unsigned)jy < 64u) && ((unsigned)jx < 64u)) {
            int j = (jy << 6) + jx;
            float oy = (float)jy + of[(b * 2 + 0) * HW + j];
            float ox = (float)jx + of[(b * 2 + 1) * HW + j];
            // truncated denominators: omitted terms < e^-25 relative
            int cy0 = min(max((int)floorf(oy), 0), 63);
            int cx0 = min(max((int)floorf(ox), 0), 63);
            float Dy = 0.f, Dx = 0.f;
            #pragma unroll
            for (int d = -3; d <= 3; ++d) {
                int iy2 = cy0 + d, ix2 = cx0 + d;
                if ((unsigned)iy2 < 64u) Dy += __expf(-TINV * fabsf(oy - (float)iy2));
                if ((unsigned)ix2 < 64u) Dx += __expf(-TINV * fabsf(ox - (float)ix2));
            }
            pv = make_float4(oy, ox, 1.f / Dy, 1.f / Dx);
        }
        pw[s] = pv;
    }

    // ---- stage 2: x window -> LDS half2 (this half's 16 channels) ----
    // (pr, row, seg) with seg fastest: 96 B contiguous per (ch-pair,row) -> coalesced
    const float* xb = x + ((size_t)((b * NC) + (h << 4)) << 12);
    for (int i = tid; i < 8 * WDIM * 6; i += 256) {
        int pr  = i / (WDIM * 6);
        int rem = i - pr * (WDIM * 6);
        int row = rem / 6, seg = rem - row * 6;
        int jy  = ty0 - RWIN + row;
        int jx0 = tx0 - RWIN + (seg << 2);   // multiple of 4: segment all-in or all-out
        unsigned int q0 = 0, q1 = 0, q2 = 0, q3 = 0;
        if (((unsigned)jy < 64u) && ((unsigned)jx0 < 61u)) {
            const float* src = xb + ((2 * pr) << 12) + (jy << 6) + jx0;
            float4 a = *(const float4*)src;          // channel 2*pr
            float4 c = *(const float4*)(src + HW);   // channel 2*pr+1
            q0 = h2_as_u32(__floats2half2_rn(a.x, c.x));
            q1 = h2_as_u32(__floats2half2_rn(a.y, c.y));
            q2 = h2_as_u32(__floats2half2_rn(a.z, c.z));
            q3 = h2_as_u32(__floats2half2_rn(a.w, c.w));
        }
        unsigned int* d = &xw[((row * WDIM + (seg << 2)) << 3) + pr];
        d[0] = q0; d[8] = q1; d[16] = q2; d[24] = q3;
    }

    __syncthreads();

    const float iy = (float)(ty0 + (lane >> 3));
    const float ix = (float)(tx0 + (lane & 7));

    __half2 acc8[8];
    #pragma unroll
    for (int c = 0; c < 8; ++c) acc8[c] = __floats2half2_rn(0.f, 0.f);

    const int srow = lane >> 5;              // 2 window rows x 32 cols per round
    const int scol = lane & 31;

    for (int r = 0; r < 3; ++r) {
        // ---- screen 64 candidates (params from LDS now) ----
        int ry = wv + srow * 4 + r * 8;      // all 24 rows over 4 waves
        int jy = ty0 - RWIN + ry;
        int jx = tx0 - RWIN + scol;
        bool valid = ((unsigned)jy < 64u) && ((unsigned)jx < 64u) && (scol < WDIM);
        int ws = ry * WDIM + min(scol, WDIM - 1);
        float4 p = pw[ws];
        float cy = fminf(fmaxf(p.x, 0.f), 63.f);
        float cx = fminf(fmaxf(p.y, 0.f), 63.f);
        float dyr = fmaxf(fmaxf((float)ty0 - cy, cy - ((float)ty0 + 7.f)), 0.f);
        float dxr = fmaxf(fmaxf((float)tx0 - cx, cx - ((float)tx0 + 7.f)), 0.f);
        bool pred = valid && (dyr + dxr < RCUT);

        unsigned long long m = __ballot(pred);
        int cnt = __popcll(m);
        if (pred) {
            int pos = __builtin_amdgcn_mbcnt_hi((unsigned)(m >> 32),
                      __builtin_amdgcn_mbcnt_lo((unsigned)m, 0u));
            wp[wv][pos] = p;
            sj[wv][pos] = ws;
        }
        // zero-weight dummy pads odd counts: p.z==0 -> g==0 exactly; x finite (xw[0])
        if (lane == cnt) { wp[wv][cnt] = make_float4(1.f, 1.f, 0.f, 0.f); sj[wv][cnt] = 0; }
        int cntp = cnt + (cnt & 1);          // even trip count, no tail selects

        // ---- FMA over survivors, 2-wide, packed fp16; x read straight from
        //      the LDS window (broadcast ds_read_b128, 32 B aligned) ----
        for (int k = 0; k < cntp; k += 2) {
            float4 p0 = wp[wv][k], p1 = wp[wv][k + 1];
            const uint4* x0 = (const uint4*)&xw[sj[wv][k]     << 3];
            const uint4* x1 = (const uint4*)&xw[sj[wv][k + 1] << 3];
            uint4 A0 = x0[0], A1 = x0[1];
            uint4 B0 = x1[0], B1 = x1[1];

            // per-dim normalize before product (fp32 overflow safety for OOB)
            float g0 = (__expf(-TINV * fabsf(p0.x - iy)) * p0.z)
                     * (__expf(-TINV * fabsf(p0.y - ix)) * p0.w);
            float g1 = (__expf(-TINV * fabsf(p1.x - iy)) * p1.z)
                     * (__expf(-TINV * fabsf(p1.y - ix)) * p1.w);
            __half2 hg0 = __float2half2_rn(g0);
            __half2 hg1 = __float2half2_rn(g1);

            acc8[0] = __hfma2(hg0, u32_as_h2(A0.x), acc8[0]);
            acc8[1] = __hfma2(hg0, u32_as_h2(A0.y), acc8[1]);
            acc8[2] = __hfma2(hg0, u32_as_h2(A0.z), acc8[2]);
            acc8[3] = __hfma2(hg0, u32_as_h2(A0.w), acc8[3]);
            acc8[4] = __hfma2(hg0, u32_as_h2(A1.x), acc8[4]);
            acc8[5] = __hfma2(hg0, u32_as_h2(A1.y), acc8[5]);
            acc8[6] = __hfma2(hg0, u32_as_h2(A1.z), acc8[6]);
            acc8[7] = __hfma2(hg0, u32_as_h2(A1.w), acc8[7]);

            acc8[0] = __hfma2(hg1, u32_as_h2(B0.x), acc8[0]);
            acc8[1] = __hfma2(hg1, u32_as_h2(B0.y), acc8[1]);
            acc8[2] = __hfma2(hg1, u32_as_h2(B0.z), acc8[2]);
            acc8[3] = __hfma2(hg1, u32_as_h2(B0.w), acc8[3]);
            acc8[4] = __hfma2(hg1, u32_as_h2(B1.x), acc8[4]);
            acc8[5] = __hfma2(hg1, u32_as_h2(B1.y), acc8[5]);
            acc8[6] = __hfma2(hg1, u32_as_h2(B1.z), acc8[6]);
            acc8[7] = __hfma2(hg1, u32_as_h2(B1.w), acc8[7]);
        }
    }

    // ---- cross-wave reduction, PACKED half2 (combine in fp32 after unpack);
    //      redu overlays pw (9216 B, exact fit) after barrier; stride 9 u32 ----
    __syncthreads();
    unsigned int* redu = (unsigned int*)pw;
    unsigned int* myr  = redu + ((wv << 6) + lane) * 9;
    #pragma unroll
    for (int c = 0; c < 8; ++c) myr[c] = h2_as_u32(acc8[c]);
    __syncthreads();

    int c2  = tid >> 5;                   // ch-pair 0..7
    int t32 = tid & 31;                   // target within tile (lo)
    #pragma unroll
    for (int k = 0; k < 2; ++k) {
        int t = t32 + 32 * k;
        float sx = 0.f, sy = 0.f;
        #pragma unroll
        for (int w = 0; w < 4; ++w) {
            float2 f = __half22float2(u32_as_h2(redu[((w << 6) + t) * 9 + c2]));
            sx += f.x; sy += f.y;
        }
        int ch   = (h << 4) + 2 * c2;
        int base = (((b << 5) + ch) << 12) + (ty0 + (t >> 3)) * 64 + (tx0 + (t & 7));
        out[base]      = sx;
        out[base + HW] = sy;
    }
}

extern "C" void kernel_launch(void* const* d_in, const int* in_sizes, int n_in,
                              void* d_out, int out_size, void* d_ws, size_t ws_size,
                              hipStream_t stream) {
    const float* x  = (const float*)d_in[0];   // [8,32,64,64]
    const float* of = (const float*)d_in[1];   // [8,2,64,64]
    float* out = (float*)d_out;                // [8,32,64,64] fp32
    (void)d_ws; (void)ws_size;                 // workspace no longer used

    warp_fused_kernel<<<dim3(64, 2, NB), dim3(256), 0, stream>>>(x, of, out);
}

// Round 2
// 70.937 us; speedup vs baseline: 1.0357x; 1.0357x over previous
//
#include <hip/hip_runtime.h>
#include <hip/hip_fp16.h>
#include <math.h>

#define HW    4096
#define NC    32
#define NB    8
#define TINV  10.0f            // 1/TEMP
#define RWIN  8                // window radius; missed sources need |of|>5.5
#define WDIM  (8 + 2 * RWIN)   // 24
#define NSRC  (WDIM * WDIM)    // 576
#define RCUT  2.0f             // rect cut; error impact unmeasurable at R12

// Fully fused, v2: xw layout is [group][src][4] (group = ch-pair quad) so the
// stage-2 LDS write is one ds_write_b128 per (group,src) with consecutive
// lanes -> consecutive src -> uniform bank coverage (floor rate). v1's layout
// ([src][8] written with pr-major threads) was a ~64-way write conflict.

__device__ __forceinline__ __half2 u32_as_h2(unsigned int u) {
    union { unsigned int u; __half2 h; } c; c.u = u; return c.h;
}
__device__ __forceinline__ unsigned int h2_as_u32(__half2 h) {
    union { __half2 h; unsigned int u; } c; c.h = h; return c.u;
}

// grid: (64 tiles, 2 channel-halves, 8 batches); 16 channels per block
__global__ __launch_bounds__(256) void warp_fused_kernel(
    const float* __restrict__ x, const float* __restrict__ of,
    float* __restrict__ out)
{
    __shared__ float4       pw[NSRC];          // window params (9216 B); redu overlays after FMA
    __shared__ unsigned int xw[2 * NSRC * 4];  // [g][src][4] half2 ch-pairs (18432 B)
    __shared__ float4       wp[4][65];         // survivor params + dummy slot
    __shared__ int          sj[4][64];         // survivor window idx

    const int b    = blockIdx.z;
    const int h    = blockIdx.y;               // channel half
    const int tile = blockIdx.x;
    const int ty0  = (tile >> 3) << 3;
    const int tx0  = (tile & 7) << 3;
    const int tid  = threadIdx.x;
    const int lane = tid & 63;
    const int wv   = __builtin_amdgcn_readfirstlane(tid >> 6);

    // ---- stage 1: params for the 24x24 window (identical math to old prep) ----
    for (int s = tid; s < NSRC; s += 256) {
        int wr = s / WDIM, wc = s - wr * WDIM;
        int jy = ty0 - RWIN + wr, jx = tx0 - RWIN + wc;
        float4 pv = make_float4(0.f, 0.f, 0.f, 0.f);
        if (((unsigned)jy < 64u) && ((unsigned)jx < 64u)) {
            int j = (jy << 6) + jx;
            float oy = (float)jy + of[(b * 2 + 0) * HW + j];
            float ox = (float)jx + of[(b * 2 + 1) * HW + j];
            // truncated denominators: omitted terms < e^-25 relative
            int cy0 = min(max((int)floorf(oy), 0), 63);
            int cx0 = min(max((int)floorf(ox), 0), 63);
            float Dy = 0.f, Dx = 0.f;
            #pragma unroll
            for (int d = -3; d <= 3; ++d) {
                int iy2 = cy0 + d, ix2 = cx0 + d;
                if ((unsigned)iy2 < 64u) Dy += __expf(-TINV * fabsf(oy - (float)iy2));
                if ((unsigned)ix2 < 64u) Dx += __expf(-TINV * fabsf(ox - (float)ix2));
            }
            pv = make_float4(oy, ox, 1.f / Dy, 1.f / Dx);
        }
        pw[s] = pv;
    }

    // ---- stage 2: x window -> LDS half2, [g][src][4] layout ----
    // task (g, src): 8 coalesced plane loads (consecutive lanes -> consecutive
    // jx), pack 4 half2, ONE ds_write_b128 at 16B-stride -> conflict-free.
    const float* xb = x + ((size_t)((b * NC) + (h << 4)) << 12);
    for (int i = tid; i < 2 * NSRC; i += 256) {
        int g   = (i >= NSRC);
        int src = i - (g ? NSRC : 0);
        int row = src / WDIM, col = src - row * WDIM;
        int jy  = ty0 - RWIN + row;
        int jx  = tx0 - RWIN + col;
        bool valid = ((unsigned)jy < 64u) && ((unsigned)jx < 64u);
        int j = valid ? ((jy << 6) + jx) : 0;
        const float* pl = xb + ((size_t)(g << 3) << 12) + j;
        float v0 = pl[0 << 12], v1 = pl[1 << 12], v2 = pl[2 << 12], v3 = pl[3 << 12];
        float v4 = pl[4 << 12], v5 = pl[5 << 12], v6 = pl[6 << 12], v7 = pl[7 << 12];
        uint4 q;
        q.x = valid ? h2_as_u32(__floats2half2_rn(v0, v1)) : 0u;
        q.y = valid ? h2_as_u32(__floats2half2_rn(v2, v3)) : 0u;
        q.z = valid ? h2_as_u32(__floats2half2_rn(v4, v5)) : 0u;
        q.w = valid ? h2_as_u32(__floats2half2_rn(v6, v7)) : 0u;
        *(uint4*)&xw[(size_t)((g ? NSRC : 0) + src) << 2] = q;
    }

    __syncthreads();

    const float iy = (float)(ty0 + (lane >> 3));
    const float ix = (float)(tx0 + (lane & 7));

    __half2 acc8[8];
    #pragma unroll
    for (int c = 0; c < 8; ++c) acc8[c] = __floats2half2_rn(0.f, 0.f);

    const int srow = lane >> 5;               // 2 window rows x 32 cols per round
    const int scol = lane & 31;
    const uint4* xwv = (const uint4*)xw;      // [g*NSRC + src]

    for (int r = 0; r < 3; ++r) {
        // ---- screen 64 candidates (params from LDS) ----
        int ry = wv + srow * 4 + r * 8;       // all 24 rows over 4 waves
        int jy = ty0 - RWIN + ry;
        int jx = tx0 - RWIN + scol;
        bool valid = ((unsigned)jy < 64u) && ((unsigned)jx < 64u) && (scol < WDIM);
        int ws = ry * WDIM + min(scol, WDIM - 1);
        float4 p = pw[ws];
        float cy = fminf(fmaxf(p.x, 0.f), 63.f);
        float cx = fminf(fmaxf(p.y, 0.f), 63.f);
        float dyr = fmaxf(fmaxf((float)ty0 - cy, cy - ((float)ty0 + 7.f)), 0.f);
        float dxr = fmaxf(fmaxf((float)tx0 - cx, cx - ((float)tx0 + 7.f)), 0.f);
        bool pred = valid && (dyr + dxr < RCUT);

        unsigned long long m = __ballot(pred);
        int cnt = __popcll(m);
        if (pred) {
            int pos = __builtin_amdgcn_mbcnt_hi((unsigned)(m >> 32),
                      __builtin_amdgcn_mbcnt_lo((unsigned)m, 0u));
            wp[wv][pos] = p;
            sj[wv][pos] = ws;
        }
        // zero-weight dummy pads odd counts: p.z==0 -> g==0 exactly; x finite (xw[0])
        if (lane == cnt) { wp[wv][cnt] = make_float4(1.f, 1.f, 0.f, 0.f); sj[wv][cnt] = 0; }
        int cntp = cnt + (cnt & 1);           // even trip count, no tail selects

        // ---- FMA over survivors, 2-wide, packed fp16; x via broadcast
        //      ds_read_b128 from the LDS window ----
        for (int k = 0; k < cntp; k += 2) {
            float4 p0 = wp[wv][k], p1 = wp[wv][k + 1];
            int s0 = sj[wv][k], s1 = sj[wv][k + 1];
            uint4 A0 = xwv[s0], A1 = xwv[NSRC + s0];
            uint4 B0 = xwv[s1], B1 = xwv[NSRC + s1];

            // per-dim normalize before product (fp32 overflow safety for OOB)
            float g0 = (__expf(-TINV * fabsf(p0.x - iy)) * p0.z)
                     * (__expf(-TINV * fabsf(p0.y - ix)) * p0.w);
            float g1 = (__expf(-TINV * fabsf(p1.x - iy)) * p1.z)
                     * (__expf(-TINV * fabsf(p1.y - ix)) * p1.w);
            __half2 hg0 = __float2half2_rn(g0);
            __half2 hg1 = __float2half2_rn(g1);

            acc8[0] = __hfma2(hg0, u32_as_h2(A0.x), acc8[0]);
            acc8[1] = __hfma2(hg0, u32_as_h2(A0.y), acc8[1]);
            acc8[2] = __hfma2(hg0, u32_as_h2(A0.z), acc8[2]);
            acc8[3] = __hfma2(hg0, u32_as_h2(A0.w), acc8[3]);
            acc8[4] = __hfma2(hg0, u32_as_h2(A1.x), acc8[4]);
            acc8[5] = __hfma2(hg0, u32_as_h2(A1.y), acc8[5]);
            acc8[6] = __hfma2(hg0, u32_as_h2(A1.z), acc8[6]);
            acc8[7] = __hfma2(hg0, u32_as_h2(A1.w), acc8[7]);

            acc8[0] = __hfma2(hg1, u32_as_h2(B0.x), acc8[0]);
            acc8[1] = __hfma2(hg1, u32_as_h2(B0.y), acc8[1]);
            acc8[2] = __hfma2(hg1, u32_as_h2(B0.z), acc8[2]);
            acc8[3] = __hfma2(hg1, u32_as_h2(B0.w), acc8[3]);
            acc8[4] = __hfma2(hg1, u32_as_h2(B1.x), acc8[4]);
            acc8[5] = __hfma2(hg1, u32_as_h2(B1.y), acc8[5]);
            acc8[6] = __hfma2(hg1, u32_as_h2(B1.z), acc8[6]);
            acc8[7] = __hfma2(hg1, u32_as_h2(B1.w), acc8[7]);
        }
    }

    // ---- cross-wave reduction, PACKED half2 (combine in fp32 after unpack);
    //      redu overlays pw (9216 B, exact fit) after barrier; stride 9 u32 ----
    __syncthreads();
    unsigned int* redu = (unsigned int*)pw;
    unsigned int* myr  = redu + ((wv << 6) + lane) * 9;
    #pragma unroll
    for (int c = 0; c < 8; ++c) myr[c] = h2_as_u32(acc8[c]);
    __syncthreads();

    int c2  = tid >> 5;                   // ch-pair 0..7
    int t32 = tid & 31;                   // target within tile (lo)
    #pragma unroll
    for (int k = 0; k < 2; ++k) {
        int t = t32 + 32 * k;
        float sx = 0.f, sy = 0.f;
        #pragma unroll
        for (int w = 0; w < 4; ++w) {
            float2 f = __half22float2(u32_as_h2(redu[((w << 6) + t) * 9 + c2]));
            sx += f.x; sy += f.y;
        }
        int ch   = (h << 4) + 2 * c2;
        int base = (((b << 5) + ch) << 12) + (ty0 + (t >> 3)) * 64 + (tx0 + (t & 7));
        out[base]      = sx;
        out[base + HW] = sy;
    }
}

extern "C" void kernel_launch(void* const* d_in, const int* in_sizes, int n_in,
                              void* d_out, int out_size, void* d_ws, size_t ws_size,
                              hipStream_t stream) {
    const float* x  = (const float*)d_in[0];   // [8,32,64,64]
    const float* of = (const float*)d_in[1];   // [8,2,64,64]
    float* out = (float*)d_out;                // [8,32,64,64] fp32
    (void)d_ws; (void)ws_size;                 // workspace no longer used

    warp_fused_kernel<<<dim3(64, 2, NB), dim3(256), 0, stream>>>(x, of, out);
}

// Round 3
// 69.518 us; speedup vs baseline: 1.0569x; 1.0204x over previous
//
#include <hip/hip_runtime.h>
#include <hip/hip_fp16.h>
#include <math.h>

#define HW    4096
#define NC    32
#define NB    8
#define TINV  10.0f            // 1/TEMP
#define RWIN  8                // window radius; missed sources need |of|>5.5
#define WDIM  (8 + 2 * RWIN)   // 24
#define NSRC  (WDIM * WDIM)    // 576
#define RCUT  2.0f             // rect cut; error impact unmeasurable at R12

// Hybrid v3: prep (once-per-image params + fp16 transpose, now at 4 blocks/CU)
// + gather that BULK-stages the 24x24 window from the pre-packed buffers into
// LDS (coalesced, conflict-free) and runs the broadcast-ds_read FMA loop.
// Strictly cheapest measured variant of every stage.

__device__ __forceinline__ __half2 u32_as_h2(unsigned int u) {
    union { unsigned int u; __half2 h; } c; c.u = u; return c.h;
}
__device__ __forceinline__ unsigned int h2_as_u32(__half2 h) {
    union { __half2 h; unsigned int u; } c; c.h = h; return c.u;
}

// grid (NB*64, 2), 256 threads: 64 j's per block, one 16-channel half.
// 1024 blocks -> 4/CU (old prep: 256 blocks = 1/CU, latency-exposed).
__global__ __launch_bounds__(256) void prep_kernel(
    const float* __restrict__ x, const float* __restrict__ of,
    float4* __restrict__ params, __half2* __restrict__ xt2)
{
    __shared__ float tile[16][66];   // stride 66: pack-read is 2-way (free)
    const int bx   = blockIdx.x;
    const int half = blockIdx.y;
    const int b    = bx >> 6;
    const int j0   = (bx & 63) << 6;
    const int t    = threadIdx.x;
    const int ch0  = half << 4;
    const int jj   = t & 63;
    const int c4   = t >> 6;         // wave index

    if (half == 0 && t < 64) {       // one wave computes this j-chunk's params
        int j = j0 + t;
        float oy = (float)(j >> 6) + of[(b * 2 + 0) * HW + j];
        float ox = (float)(j & 63) + of[(b * 2 + 1) * HW + j];
        // truncated denominators: omitted terms < e^-25 relative
        int cy0 = min(max((int)floorf(oy), 0), 63);
        int cx0 = min(max((int)floorf(ox), 0), 63);
        float Dy = 0.f, Dx = 0.f;
        #pragma unroll
        for (int d = -3; d <= 3; ++d) {
            int iy = cy0 + d, ix = cx0 + d;
            if ((unsigned)iy < 64u) Dy += __expf(-TINV * fabsf(oy - (float)iy));
            if ((unsigned)ix < 64u) Dx += __expf(-TINV * fabsf(ox - (float)ix));
        }
        params[(b << 12) + j] = make_float4(oy, ox, 1.f / Dy, 1.f / Dx);
    }

    // per wave: 4 channels, 64-wide coalesced loads; conflict-free tile writes
    #pragma unroll
    for (int k = 0; k < 4; ++k) {
        int c = c4 * 4 + k;
        tile[c][jj] = x[((size_t)(b * NC + ch0 + c) << 12) + j0 + jj];
    }
    __syncthreads();
    // pack 512 half2 (same pairing as baseline -> bit-identical values)
    #pragma unroll
    for (int k = 0; k < 2; ++k) {
        int s  = k * 256 + t;
        int j2 = s >> 3, pr = s & 7;
        xt2[((size_t)((b << 12) + j0 + j2) << 4) + (half << 3) + pr] =
            __floats2half2_rn(tile[2 * pr][j2], tile[2 * pr + 1][j2]);
    }
}

// grid: (64 tiles, 2 channel-halves, 8 batches); 16 channels per block
__global__ __launch_bounds__(256) void gather_kernel(
    const float4* __restrict__ params, const unsigned int* __restrict__ xtu,
    float* __restrict__ out)
{
    __shared__ float4       pw[NSRC];        // window params (9216 B); redu overlay
    __shared__ unsigned int xw[NSRC * 8];    // window x [src][8 u32] (18432 B)
    __shared__ float4       wp[4][65];       // survivor params + dummy slot
    __shared__ int          sj[4][64];       // survivor window idx

    const int b    = blockIdx.z;
    const int h    = blockIdx.y;             // channel half
    const int tile = blockIdx.x;
    const int ty0  = (tile >> 3) << 3;
    const int tx0  = (tile & 7) << 3;
    const int tid  = threadIdx.x;
    const int lane = tid & 63;
    const int wv   = __builtin_amdgcn_readfirstlane(tid >> 6);

    // ---- stage params window: coalesced float4 copies, 2.25/thread ----
    const float4* pb = params + (b << 12);
    for (int s = tid; s < NSRC; s += 256) {
        int wr = s / WDIM, wc = s - wr * WDIM;
        int jy = ty0 - RWIN + wr, jx = tx0 - RWIN + wc;
        bool v = ((unsigned)jy < 64u) && ((unsigned)jx < 64u);
        pw[s] = v ? pb[(jy << 6) + jx] : make_float4(0.f, 0.f, 0.f, 0.f);
    }

    // ---- stage x window from pre-packed xt2: 4.5 uint4/thread, 16B-stride
    //      LDS writes (conflict-free) ----
    const unsigned int* xb = xtu + ((size_t)(b << 12) << 4) + (h << 3);
    for (int i = tid; i < 2 * NSRC; i += 256) {
        int src = i >> 1, e = i & 1;
        int wr = src / WDIM, wc = src - wr * WDIM;
        int jy = ty0 - RWIN + wr, jx = tx0 - RWIN + wc;
        bool v = ((unsigned)jy < 64u) && ((unsigned)jx < 64u);
        uint4 q = make_uint4(0u, 0u, 0u, 0u);
        if (v) q = *(const uint4*)(xb + (((size_t)((jy << 6) + jx)) << 4) + (e << 2));
        *(uint4*)&xw[(size_t)i << 2] = q;    // dword addr i*4 = src*8 + e*4
    }

    __syncthreads();

    const float iy = (float)(ty0 + (lane >> 3));
    const float ix = (float)(tx0 + (lane & 7));

    __half2 acc8[8];
    #pragma unroll
    for (int c = 0; c < 8; ++c) acc8[c] = __floats2half2_rn(0.f, 0.f);

    const int srow = lane >> 5;              // 2 window rows x 32 cols per round
    const int scol = lane & 31;

    for (int r = 0; r < 3; ++r) {
        // ---- screen 64 candidates (params from LDS) ----
        int ry = wv + srow * 4 + r * 8;      // all 24 rows over 4 waves
        int jy = ty0 - RWIN + ry;
        int jx = tx0 - RWIN + scol;
        bool valid = ((unsigned)jy < 64u) && ((unsigned)jx < 64u) && (scol < WDIM);
        int ws = ry * WDIM + min(scol, WDIM - 1);
        float4 p = pw[ws];
        float cy = fminf(fmaxf(p.x, 0.f), 63.f);
        float cx = fminf(fmaxf(p.y, 0.f), 63.f);
        float dyr = fmaxf(fmaxf((float)ty0 - cy, cy - ((float)ty0 + 7.f)), 0.f);
        float dxr = fmaxf(fmaxf((float)tx0 - cx, cx - ((float)tx0 + 7.f)), 0.f);
        bool pred = valid && (dyr + dxr < RCUT);

        unsigned long long m = __ballot(pred);
        int cnt = __popcll(m);
        if (pred) {
            int pos = __builtin_amdgcn_mbcnt_hi((unsigned)(m >> 32),
                      __builtin_amdgcn_mbcnt_lo((unsigned)m, 0u));
            wp[wv][pos] = p;
            sj[wv][pos] = ws;
        }
        // zero-weight dummy pads odd counts: p.z==0 -> g==0 exactly; x finite
        if (lane == cnt) { wp[wv][cnt] = make_float4(1.f, 1.f, 0.f, 0.f); sj[wv][cnt] = 0; }
        int cntp = cnt + (cnt & 1);          // even trip count, no tail selects

        // ---- FMA over survivors, 2-wide, packed fp16; x via broadcast
        //      ds_read_b128 (uniform address -> no conflicts) ----
        for (int k = 0; k < cntp; k += 2) {
            float4 p0 = wp[wv][k], p1 = wp[wv][k + 1];
            int s0 = sj[wv][k], s1 = sj[wv][k + 1];
            const uint4* x0 = (const uint4*)&xw[(size_t)s0 << 3];
            const uint4* x1 = (const uint4*)&xw[(size_t)s1 << 3];
            uint4 A0 = x0[0], A1 = x0[1];
            uint4 B0 = x1[0], B1 = x1[1];

            // per-dim normalize before product (fp32 overflow safety for OOB)
            float g0 = (__expf(-TINV * fabsf(p0.x - iy)) * p0.z)
                     * (__expf(-TINV * fabsf(p0.y - ix)) * p0.w);
            float g1 = (__expf(-TINV * fabsf(p1.x - iy)) * p1.z)
                     * (__expf(-TINV * fabsf(p1.y - ix)) * p1.w);
            __half2 hg0 = __float2half2_rn(g0);
            __half2 hg1 = __float2half2_rn(g1);

            acc8[0] = __hfma2(hg0, u32_as_h2(A0.x), acc8[0]);
            acc8[1] = __hfma2(hg0, u32_as_h2(A0.y), acc8[1]);
            acc8[2] = __hfma2(hg0, u32_as_h2(A0.z), acc8[2]);
            acc8[3] = __hfma2(hg0, u32_as_h2(A0.w), acc8[3]);
            acc8[4] = __hfma2(hg0, u32_as_h2(A1.x), acc8[4]);
            acc8[5] = __hfma2(hg0, u32_as_h2(A1.y), acc8[5]);
            acc8[6] = __hfma2(hg0, u32_as_h2(A1.z), acc8[6]);
            acc8[7] = __hfma2(hg0, u32_as_h2(A1.w), acc8[7]);

            acc8[0] = __hfma2(hg1, u32_as_h2(B0.x), acc8[0]);
            acc8[1] = __hfma2(hg1, u32_as_h2(B0.y), acc8[1]);
            acc8[2] = __hfma2(hg1, u32_as_h2(B0.z), acc8[2]);
            acc8[3] = __hfma2(hg1, u32_as_h2(B0.w), acc8[3]);
            acc8[4] = __hfma2(hg1, u32_as_h2(B1.x), acc8[4]);
            acc8[5] = __hfma2(hg1, u32_as_h2(B1.y), acc8[5]);
            acc8[6] = __hfma2(hg1, u32_as_h2(B1.z), acc8[6]);
            acc8[7] = __hfma2(hg1, u32_as_h2(B1.w), acc8[7]);
        }
    }

    // ---- cross-wave reduction, PACKED half2 (combine in fp32 after unpack);
    //      redu overlays pw (9216 B, exact fit); stride 9 u32 -> conflict-free ----
    __syncthreads();
    unsigned int* redu = (unsigned int*)pw;
    unsigned int* myr  = redu + ((wv << 6) + lane) * 9;
    #pragma unroll
    for (int c = 0; c < 8; ++c) myr[c] = h2_as_u32(acc8[c]);
    __syncthreads();

    int c2  = tid >> 5;                   // ch-pair 0..7
    int t32 = tid & 31;                   // target within tile (lo)
    #pragma unroll
    for (int k = 0; k < 2; ++k) {
        int t = t32 + 32 * k;
        float sx = 0.f, sy = 0.f;
        #pragma unroll
        for (int w = 0; w < 4; ++w) {
            float2 f = __half22float2(u32_as_h2(redu[((w << 6) + t) * 9 + c2]));
            sx += f.x; sy += f.y;
        }
        int ch   = (h << 4) + 2 * c2;
        int base = (((b << 5) + ch) << 12) + (ty0 + (t >> 3)) * 64 + (tx0 + (t & 7));
        out[base]      = sx;
        out[base + HW] = sy;
    }
}

extern "C" void kernel_launch(void* const* d_in, const int* in_sizes, int n_in,
                              void* d_out, int out_size, void* d_ws, size_t ws_size,
                              hipStream_t stream) {
    const float* x  = (const float*)d_in[0];   // [8,32,64,64]
    const float* of = (const float*)d_in[1];   // [8,2,64,64]
    float* out = (float*)d_out;                // [8,32,64,64] fp32

    float4*  params = (float4*)d_ws;                                      // 512 KB
    __half2* xt2    = (__half2*)((char*)d_ws + NB * HW * sizeof(float4)); // 2 MB

    prep_kernel<<<dim3(NB * 64, 2), dim3(256), 0, stream>>>(x, of, params, xt2);
    gather_kernel<<<dim3(64, 2, NB), dim3(256), 0, stream>>>(
        params, (const unsigned int*)xt2, out);
}

// Round 4
// 67.864 us; speedup vs baseline: 1.0826x; 1.0244x over previous
//
#include <hip/hip_runtime.h>
#include <hip/hip_fp16.h>
#include <math.h>

#define HW    4096
#define NC    32
#define NB    8
#define TINV  10.0f            // 1/TEMP
#define RWIN  8                // window radius; missed sources need |of|>5.5
#define WDIM  (8 + 2 * RWIN)   // 24
#define RCUT  2.0f             // rect cut; error impact unmeasurable at R12

// v4: measured-best gather structure (direct-global screen + survivor-only
// staging + broadcast-LDS FMA) with the two channel-halves MERGED into one
// block (32 ch, 64 B survivor records): halves chip-wide screen/param/exp
// work. Prep kept from v3 (1024 blocks = 4/CU).

__device__ __forceinline__ __half2 u32_as_h2(unsigned int u) {
    union { unsigned int u; __half2 h; } c; c.u = u; return c.h;
}
__device__ __forceinline__ unsigned int h2_as_u32(__half2 h) {
    union { __half2 h; unsigned int u; } c; c.h = h; return c.u;
}

// grid (NB*64, 2), 256 threads: 64 j's per block, one 16-channel half.
__global__ __launch_bounds__(256) void prep_kernel(
    const float* __restrict__ x, const float* __restrict__ of,
    float4* __restrict__ params, __half2* __restrict__ xt2)
{
    __shared__ float tile[16][66];   // stride 66: pack-read is 2-way (free)
    const int bx   = blockIdx.x;
    const int half = blockIdx.y;
    const int b    = bx >> 6;
    const int j0   = (bx & 63) << 6;
    const int t    = threadIdx.x;
    const int ch0  = half << 4;
    const int jj   = t & 63;
    const int c4   = t >> 6;         // wave index

    if (half == 0 && t < 64) {       // one wave computes this j-chunk's params
        int j = j0 + t;
        float oy = (float)(j >> 6) + of[(b * 2 + 0) * HW + j];
        float ox = (float)(j & 63) + of[(b * 2 + 1) * HW + j];
        // truncated denominators: omitted terms < e^-25 relative
        int cy0 = min(max((int)floorf(oy), 0), 63);
        int cx0 = min(max((int)floorf(ox), 0), 63);
        float Dy = 0.f, Dx = 0.f;
        #pragma unroll
        for (int d = -3; d <= 3; ++d) {
            int iy = cy0 + d, ix = cx0 + d;
            if ((unsigned)iy < 64u) Dy += __expf(-TINV * fabsf(oy - (float)iy));
            if ((unsigned)ix < 64u) Dx += __expf(-TINV * fabsf(ox - (float)ix));
        }
        params[(b << 12) + j] = make_float4(oy, ox, 1.f / Dy, 1.f / Dx);
    }

    // per wave: 4 channels, 64-wide coalesced loads; conflict-free tile writes
    #pragma unroll
    for (int k = 0; k < 4; ++k) {
        int c = c4 * 4 + k;
        tile[c][jj] = x[((size_t)(b * NC + ch0 + c) << 12) + j0 + jj];
    }
    __syncthreads();
    // pack 512 half2 (same pairing as baseline -> bit-identical values)
    #pragma unroll
    for (int k = 0; k < 2; ++k) {
        int s  = k * 256 + t;
        int j2 = s >> 3, pr = s & 7;
        xt2[((size_t)((b << 12) + j0 + j2) << 4) + (half << 3) + pr] =
            __floats2half2_rn(tile[2 * pr][j2], tile[2 * pr + 1][j2]);
    }
}

// grid: (64 tiles, 8 batches); ALL 32 channels per block
__global__ __launch_bounds__(256) void gather_kernel(
    const float4* __restrict__ params, const unsigned int* __restrict__ xtu,
    float* __restrict__ out)
{
    __shared__ float4       wp[4][65];          // survivor params + dummy slot
    __shared__ int          sj[4][64];          // survivor source idx
    __shared__ unsigned int pool[4 * 64 * 17];  // 17 KB: XSu (stride 16), redu (stride 17)

    const int b    = blockIdx.y;
    const int tile = blockIdx.x;
    const int ty0  = (tile >> 3) << 3;
    const int tx0  = (tile & 7) << 3;

    const int tid  = threadIdx.x;
    const int lane = tid & 63;
    const int wv   = __builtin_amdgcn_readfirstlane(tid >> 6);

    const float iy = (float)(ty0 + (lane >> 3));
    const float ix = (float)(tx0 + (lane & 7));

    __half2 acc16[16];
    #pragma unroll
    for (int c = 0; c < 16; ++c) acc16[c] = __floats2half2_rn(0.f, 0.f);

    const float4*       pb = params + (b << 12);
    const unsigned int* xb = xtu + ((size_t)(b << 12) << 4);  // 16 u32 per src

    const int srow = lane >> 5;           // 2 window rows x 32 cols per round
    const int scol = lane & 31;

    unsigned int* XSu = pool;             // [wv*64+s]*16 u32 per survivor

    for (int r = 0; r < 3; ++r) {
        // ---- screen 64 candidates (direct global param read) ----
        int ry = wv + srow * 4 + r * 8;   // all 24 rows over 4 waves
        int jy = ty0 - RWIN + ry;
        int jx = tx0 - RWIN + scol;
        bool valid = ((unsigned)jy < 64u) && ((unsigned)jx < 64u) && (scol < WDIM);
        int j = (jy << 6) + jx;
        float4 p = pb[valid ? j : 0];
        float cy = fminf(fmaxf(p.x, 0.f), 63.f);
        float cx = fminf(fmaxf(p.y, 0.f), 63.f);
        float dyr = fmaxf(fmaxf((float)ty0 - cy, cy - ((float)ty0 + 7.f)), 0.f);
        float dxr = fmaxf(fmaxf((float)tx0 - cx, cx - ((float)tx0 + 7.f)), 0.f);
        bool pred = valid && (dyr + dxr < RCUT);

        unsigned long long m = __ballot(pred);
        int cnt = __popcll(m);
        if (pred) {
            int pos = __builtin_amdgcn_mbcnt_hi((unsigned)(m >> 32),
                      __builtin_amdgcn_mbcnt_lo((unsigned)m, 0u));
            wp[wv][pos] = p;
            sj[wv][pos] = j;
        }
        // zero-weight dummy pads odd counts: p.z==0 -> g==0 exactly
        if (lane == cnt) wp[wv][cnt] = make_float4(1.f, 1.f, 0.f, 0.f);
        int cntp = cnt + (cnt & 1);       // even trip count, no tail selects

        // ---- stage survivors' x: 4 lanes x 16 B = 64 B/surv, 16 surv/pass ----
        // (dummy slot staged with last survivor's data: finite, weight 0)
        for (int m4 = 0; m4 < cntp; m4 += 16) {
            int s = m4 + (lane >> 2);
            if (s < cntp) {
                int jj = sj[wv][min(s, cnt - 1)];
                const uint4* src = (const uint4*)(xb + (size_t)jj * 16 + ((lane & 3) << 2));
                *(uint4*)&XSu[(((wv << 6) + s) << 4) + ((lane & 3) << 2)] = *src;
            }
        }

        // ---- FMA over survivors, 2-wide, packed fp16, 32 ch ----
        for (int k = 0; k < cntp; k += 2) {
            float4 p0 = wp[wv][k], p1 = wp[wv][k + 1];
            const uint4* x0 = (const uint4*)&XSu[((wv << 6) + k)     << 4];
            const uint4* x1 = (const uint4*)&XSu[((wv << 6) + k + 1) << 4];
            uint4 A[4], B[4];
            #pragma unroll
            for (int q = 0; q < 4; ++q) { A[q] = x0[q]; B[q] = x1[q]; }

            // per-dim normalize before product (fp32 overflow safety for OOB)
            float g0 = (__expf(-TINV * fabsf(p0.x - iy)) * p0.z)
                     * (__expf(-TINV * fabsf(p0.y - ix)) * p0.w);
            float g1 = (__expf(-TINV * fabsf(p1.x - iy)) * p1.z)
                     * (__expf(-TINV * fabsf(p1.y - ix)) * p1.w);
            __half2 hg0 = __float2half2_rn(g0);
            __half2 hg1 = __float2half2_rn(g1);

            #pragma unroll
            for (int q = 0; q < 4; ++q) {
                acc16[4 * q + 0] = __hfma2(hg0, u32_as_h2(A[q].x), acc16[4 * q + 0]);
                acc16[4 * q + 1] = __hfma2(hg0, u32_as_h2(A[q].y), acc16[4 * q + 1]);
                acc16[4 * q + 2] = __hfma2(hg0, u32_as_h2(A[q].z), acc16[4 * q + 2]);
                acc16[4 * q + 3] = __hfma2(hg0, u32_as_h2(A[q].w), acc16[4 * q + 3]);
            }
            #pragma unroll
            for (int q = 0; q < 4; ++q) {
                acc16[4 * q + 0] = __hfma2(hg1, u32_as_h2(B[q].x), acc16[4 * q + 0]);
                acc16[4 * q + 1] = __hfma2(hg1, u32_as_h2(B[q].y), acc16[4 * q + 1]);
                acc16[4 * q + 2] = __hfma2(hg1, u32_as_h2(B[q].z), acc16[4 * q + 2]);
                acc16[4 * q + 3] = __hfma2(hg1, u32_as_h2(B[q].w), acc16[4 * q + 3]);
            }
        }
    }

    // ---- cross-wave reduction, PACKED half2; redu overlays XSu after
    //      barrier; stride 17 u32 (odd) -> conflict-free ----
    __syncthreads();
    unsigned int* redu = pool;
    unsigned int* myr  = redu + (unsigned)tid * 17;
    #pragma unroll
    for (int c = 0; c < 16; ++c) myr[c] = h2_as_u32(acc16[c]);
    __syncthreads();

    int t  = tid & 63;                    // target within tile
    int c0 = tid >> 6;                    // base ch-pair 0..3
    #pragma unroll
    for (int k = 0; k < 4; ++k) {
        int c2 = c0 + (k << 2);           // ch-pair 0..15
        float sx = 0.f, sy = 0.f;
        #pragma unroll
        for (int w = 0; w < 4; ++w) {
            float2 f = __half22float2(u32_as_h2(redu[(unsigned)((w << 6) + t) * 17 + c2]));
            sx += f.x; sy += f.y;
        }
        int ch   = c2 << 1;
        int base = (((b << 5) + ch) << 12) + (ty0 + (t >> 3)) * 64 + (tx0 + (t & 7));
        out[base]      = sx;
        out[base + HW] = sy;
    }
}

extern "C" void kernel_launch(void* const* d_in, const int* in_sizes, int n_in,
                              void* d_out, int out_size, void* d_ws, size_t ws_size,
                              hipStream_t stream) {
    const float* x  = (const float*)d_in[0];   // [8,32,64,64]
    const float* of = (const float*)d_in[1];   // [8,2,64,64]
    float* out = (float*)d_out;                // [8,32,64,64] fp32

    float4*  params = (float4*)d_ws;                                      // 512 KB
    __half2* xt2    = (__half2*)((char*)d_ws + NB * HW * sizeof(float4)); // 2 MB

    prep_kernel<<<dim3(NB * 64, 2), dim3(256), 0, stream>>>(x, of, params, xt2);
    gather_kernel<<<dim3(64, NB), dim3(256), 0, stream>>>(
        params, (const unsigned int*)xt2, out);
}

// Round 5
// 66.567 us; speedup vs baseline: 1.1037x; 1.0195x over previous
//
#include <hip/hip_runtime.h>
#include <hip/hip_fp16.h>
#include <math.h>

#define HW    4096
#define NC    32
#define NB    8
#define TINV  10.0f            // 1/TEMP
#define RWIN  8                // window radius; missed sources need |of|>5.5
#define WDIM  (8 + 2 * RWIN)   // 24
#define RCUT  2.0f             // rect cut; error impact unmeasurable at R12
#define MAXS  148              // per-wave survivor cap (3 rounds x 48 + pad)

// v5: v4 (merged 32-ch gather) + latency pipelining:
//  - all 3 rounds' param loads issued upfront (1 exposed latency, not 3)
//  - one merged survivor list per wave; staging in 32-survivor chunks,
//    double-buffered, T14 split (load chunk c+1 -> FMA chunk c -> write c+1)
// Survivor order & fp16 accumulation sequence identical to v4 -> same output.

__device__ __forceinline__ __half2 u32_as_h2(unsigned int u) {
    union { unsigned int u; __half2 h; } c; c.u = u; return c.h;
}
__device__ __forceinline__ unsigned int h2_as_u32(__half2 h) {
    union { __half2 h; unsigned int u; } c; c.h = h; return c.u;
}

// grid (NB*64, 2), 256 threads: 64 j's per block, one 16-channel half.
__global__ __launch_bounds__(256) void prep_kernel(
    const float* __restrict__ x, const float* __restrict__ of,
    float4* __restrict__ params, __half2* __restrict__ xt2)
{
    __shared__ float tile[16][66];   // stride 66: pack-read is 2-way (free)
    const int bx   = blockIdx.x;
    const int half = blockIdx.y;
    const int b    = bx >> 6;
    const int j0   = (bx & 63) << 6;
    const int t    = threadIdx.x;
    const int ch0  = half << 4;
    const int jj   = t & 63;
    const int c4   = t >> 6;         // wave index

    if (half == 0 && t < 64) {       // one wave computes this j-chunk's params
        int j = j0 + t;
        float oy = (float)(j >> 6) + of[(b * 2 + 0) * HW + j];
        float ox = (float)(j & 63) + of[(b * 2 + 1) * HW + j];
        // truncated denominators: omitted terms < e^-25 relative
        int cy0 = min(max((int)floorf(oy), 0), 63);
        int cx0 = min(max((int)floorf(ox), 0), 63);
        float Dy = 0.f, Dx = 0.f;
        #pragma unroll
        for (int d = -3; d <= 3; ++d) {
            int iy = cy0 + d, ix = cx0 + d;
            if ((unsigned)iy < 64u) Dy += __expf(-TINV * fabsf(oy - (float)iy));
            if ((unsigned)ix < 64u) Dx += __expf(-TINV * fabsf(ox - (float)ix));
        }
        params[(b << 12) + j] = make_float4(oy, ox, 1.f / Dy, 1.f / Dx);
    }

    // per wave: 4 channels, 64-wide coalesced loads; conflict-free tile writes
    #pragma unroll
    for (int k = 0; k < 4; ++k) {
        int c = c4 * 4 + k;
        tile[c][jj] = x[((size_t)(b * NC + ch0 + c) << 12) + j0 + jj];
    }
    __syncthreads();
    // pack 512 half2 (same pairing as baseline -> bit-identical values)
    #pragma unroll
    for (int k = 0; k < 2; ++k) {
        int s  = k * 256 + t;
        int j2 = s >> 3, pr = s & 7;
        xt2[((size_t)((b << 12) + j0 + j2) << 4) + (half << 3) + pr] =
            __floats2half2_rn(tile[2 * pr][j2], tile[2 * pr + 1][j2]);
    }
}

// grid: (64 tiles, 8 batches); ALL 32 channels per block
__global__ __launch_bounds__(256) void gather_kernel(
    const float4* __restrict__ params, const unsigned int* __restrict__ xtu,
    float* __restrict__ out)
{
    // pool layout (u32): wp 4*MAXS*4 | sj 4*MAXS | XS 4 waves * 2 bufs * 512
    __shared__ __align__(16) unsigned int pool[4 * MAXS * 4 + 4 * MAXS + 4096];

    const int b    = blockIdx.y;
    const int tile = blockIdx.x;
    const int ty0  = (tile >> 3) << 3;
    const int tx0  = (tile & 7) << 3;

    const int tid  = threadIdx.x;
    const int lane = tid & 63;
    const int wv   = __builtin_amdgcn_readfirstlane(tid >> 6);

    float4*       wpW = ((float4*)pool) + wv * MAXS;
    int*          sjW = ((int*)pool) + 4 * MAXS * 4 + wv * MAXS;
    unsigned int* XSW = pool + 4 * MAXS * 4 + 4 * MAXS + wv * 1024;

    const float iy = (float)(ty0 + (lane >> 3));
    const float ix = (float)(tx0 + (lane & 7));

    __half2 acc16[16];
    #pragma unroll
    for (int c = 0; c < 16; ++c) acc16[c] = __floats2half2_rn(0.f, 0.f);

    const float4*       pb = params + (b << 12);
    const unsigned int* xb = xtu + ((size_t)(b << 12) << 4);  // 16 u32 per src

    const int srow = lane >> 5;           // 2 window rows x 32 cols per round
    const int scol = lane & 31;

    // ---- screen: all 3 rounds' param loads issued together ----
    float4 pr3[3]; int jr3[3]; bool va3[3];
    #pragma unroll
    for (int r = 0; r < 3; ++r) {
        int ry = wv + srow * 4 + r * 8;   // all 24 rows over 4 waves
        int jy = ty0 - RWIN + ry;
        int jx = tx0 - RWIN + scol;
        bool valid = ((unsigned)jy < 64u) && ((unsigned)jx < 64u) && (scol < WDIM);
        int j = (jy << 6) + jx;
        va3[r] = valid; jr3[r] = j;
        pr3[r] = pb[valid ? j : 0];
    }

    // ---- compact into one per-wave survivor list (order == v4's) ----
    int total = 0;
    #pragma unroll
    for (int r = 0; r < 3; ++r) {
        float4 p = pr3[r];
        float cy = fminf(fmaxf(p.x, 0.f), 63.f);
        float cx = fminf(fmaxf(p.y, 0.f), 63.f);
        float dyr = fmaxf(fmaxf((float)ty0 - cy, cy - ((float)ty0 + 7.f)), 0.f);
        float dxr = fmaxf(fmaxf((float)tx0 - cx, cx - ((float)tx0 + 7.f)), 0.f);
        bool pred = va3[r] && (dyr + dxr < RCUT);
        unsigned long long m = __ballot(pred);
        if (pred) {
            int pos = total + __builtin_amdgcn_mbcnt_hi((unsigned)(m >> 32),
                              __builtin_amdgcn_mbcnt_lo((unsigned)m, 0u));
            wpW[pos] = p;
            sjW[pos] = jr3[r];
        }
        total += __popcll(m);
    }
    // zero-weight dummy pads odd totals: p.z==0 -> g==0 exactly; x finite
    if ((total & 1) && lane == 0) {
        wpW[total] = make_float4(1.f, 1.f, 0.f, 0.f);
        sjW[total] = sjW[0];
    }
    const int padT = total + (total & 1);
    const int nch  = (padT + 31) >> 5;

    // ---- staging helpers: 2 lanes x 32 B per survivor, 32 surv/chunk ----
    auto stage_load = [&](int c, uint4& A, uint4& B) {
        int s = (c << 5) + (lane >> 1);
        A = make_uint4(0u, 0u, 0u, 0u); B = A;
        if (s < padT) {
            const unsigned int* src = xb + (size_t)sjW[s] * 16 + ((lane & 1) << 3);
            A = *(const uint4*)src;
            B = *(const uint4*)(src + 4);
        }
    };
    auto stage_write = [&](int c, uint4 A, uint4 B) {
        unsigned int* d = XSW + ((c & 1) << 9) + (lane << 3);
        *(uint4*)d       = A;
        *(uint4*)(d + 4) = B;
    };

    // ---- pipelined FMA: load c+1 -> FMA c (LDS broadcast) -> write c+1 ----
    if (nch > 0) {
        uint4 a0, b0;
        stage_load(0, a0, b0);
        stage_write(0, a0, b0);
        for (int c = 0; c < nch; ++c) {
            uint4 na, nb;
            const bool more = (c + 1) < nch;
            if (more) stage_load(c + 1, na, nb);

            int cnt_c = min(32, padT - (c << 5));
            const uint4* XR = (const uint4*)(XSW + ((c & 1) << 9));
            for (int k = 0; k < cnt_c; k += 2) {
                float4 p0 = wpW[(c << 5) + k], p1 = wpW[(c << 5) + k + 1];
                const uint4* x0 = XR + (k << 2);
                const uint4* x1 = XR + ((k + 1) << 2);
                uint4 A[4], Bv[4];
                #pragma unroll
                for (int q = 0; q < 4; ++q) { A[q] = x0[q]; Bv[q] = x1[q]; }

                // per-dim normalize before product (fp32 overflow safety)
                float g0 = (__expf(-TINV * fabsf(p0.x - iy)) * p0.z)
                         * (__expf(-TINV * fabsf(p0.y - ix)) * p0.w);
                float g1 = (__expf(-TINV * fabsf(p1.x - iy)) * p1.z)
                         * (__expf(-TINV * fabsf(p1.y - ix)) * p1.w);
                __half2 hg0 = __float2half2_rn(g0);
                __half2 hg1 = __float2half2_rn(g1);

                #pragma unroll
                for (int q = 0; q < 4; ++q) {
                    acc16[4 * q + 0] = __hfma2(hg0, u32_as_h2(A[q].x), acc16[4 * q + 0]);
                    acc16[4 * q + 1] = __hfma2(hg0, u32_as_h2(A[q].y), acc16[4 * q + 1]);
                    acc16[4 * q + 2] = __hfma2(hg0, u32_as_h2(A[q].z), acc16[4 * q + 2]);
                    acc16[4 * q + 3] = __hfma2(hg0, u32_as_h2(A[q].w), acc16[4 * q + 3]);
                }
                #pragma unroll
                for (int q = 0; q < 4; ++q) {
                    acc16[4 * q + 0] = __hfma2(hg1, u32_as_h2(Bv[q].x), acc16[4 * q + 0]);
                    acc16[4 * q + 1] = __hfma2(hg1, u32_as_h2(Bv[q].y), acc16[4 * q + 1]);
                    acc16[4 * q + 2] = __hfma2(hg1, u32_as_h2(Bv[q].z), acc16[4 * q + 2]);
                    acc16[4 * q + 3] = __hfma2(hg1, u32_as_h2(Bv[q].w), acc16[4 * q + 3]);
                }
            }
            if (more) stage_write(c + 1, na, nb);
        }
    }

    // ---- cross-wave reduction, PACKED half2; redu overlays pool after
    //      barrier; stride 17 u32 (odd) -> conflict-free ----
    __syncthreads();
    unsigned int* redu = pool;
    unsigned int* myr  = redu + (unsigned)tid * 17;
    #pragma unroll
    for (int c = 0; c < 16; ++c) myr[c] = h2_as_u32(acc16[c]);
    __syncthreads();

    int t  = tid & 63;                    // target within tile
    int c0 = tid >> 6;                    // base ch-pair 0..3
    #pragma unroll
    for (int k = 0; k < 4; ++k) {
        int c2 = c0 + (k << 2);           // ch-pair 0..15
        float sx = 0.f, sy = 0.f;
        #pragma unroll
        for (int w = 0; w < 4; ++w) {
            float2 f = __half22float2(u32_as_h2(redu[(unsigned)((w << 6) + t) * 17 + c2]));
            sx += f.x; sy += f.y;
        }
        int ch   = c2 << 1;
        int base = (((b << 5) + ch) << 12) + (ty0 + (t >> 3)) * 64 + (tx0 + (t & 7));
        out[base]      = sx;
        out[base + HW] = sy;
    }
}

extern "C" void kernel_launch(void* const* d_in, const int* in_sizes, int n_in,
                              void* d_out, int out_size, void* d_ws, size_t ws_size,
                              hipStream_t stream) {
    const float* x  = (const float*)d_in[0];   // [8,32,64,64]
    const float* of = (const float*)d_in[1];   // [8,2,64,64]
    float* out = (float*)d_out;                // [8,32,64,64] fp32

    float4*  params = (float4*)d_ws;                                      // 512 KB
    __half2* xt2    = (__half2*)((char*)d_ws + NB * HW * sizeof(float4)); // 2 MB

    prep_kernel<<<dim3(NB * 64, 2), dim3(256), 0, stream>>>(x, of, params, xt2);
    gather_kernel<<<dim3(64, NB), dim3(256), 0, stream>>>(
        params, (const unsigned int*)xt2, out);
}

// Round 6
// 65.511 us; speedup vs baseline: 1.1215x; 1.0161x over previous
//
#include <hip/hip_runtime.h>
#include <hip/hip_fp16.h>
#include <math.h>

#define HW    4096
#define NC    32
#define NB    8
#define TINV  10.0f            // 1/TEMP
#define RWIN  8                // window radius; missed sources need |of|>5.5
#define WDIM  (8 + 2 * RWIN)   // 24
#define RCUT  1.2f             // rect cut; boundary weight e^-12 ~ 6e-6 rel
#define MAXS  148              // per-wave survivor cap (worst case 144 + pad)

// v6: v5 + (a) RCUT 2.0->1.2 (-25% survivors, error budget e^-12),
// (b) prep merges both channel halves: one 512-block kernel, 32-ch LDS
// transpose (2-way reads = free), ONE coalesced uint4 xt2 store per thread.

__device__ __forceinline__ __half2 u32_as_h2(unsigned int u) {
    union { unsigned int u; __half2 h; } c; c.u = u; return c.h;
}
__device__ __forceinline__ unsigned int h2_as_u32(__half2 h) {
    union { __half2 h; unsigned int u; } c; c.h = h; return c.u;
}

// grid (NB*64), 256 threads: 64 j's per block, ALL 32 channels.
__global__ __launch_bounds__(256) void prep_kernel(
    const float* __restrict__ x, const float* __restrict__ of,
    float4* __restrict__ params, unsigned int* __restrict__ xt2u)
{
    __shared__ float tile[32][66];   // 8.25 KB; stride 66 -> 2-way reads (free)
    const int bx = blockIdx.x;
    const int b  = bx >> 6;
    const int j0 = (bx & 63) << 6;
    const int t  = threadIdx.x;
    const int jj = t & 63;
    const int wN = t >> 6;           // wave index 0..3

    if (t < 64) {                    // one wave computes this chunk's params
        int j = j0 + t;
        float oy = (float)(j >> 6) + of[(b * 2 + 0) * HW + j];
        float ox = (float)(j & 63) + of[(b * 2 + 1) * HW + j];
        // truncated denominators: omitted terms < e^-25 relative
        int cy0 = min(max((int)floorf(oy), 0), 63);
        int cx0 = min(max((int)floorf(ox), 0), 63);
        float Dy = 0.f, Dx = 0.f;
        #pragma unroll
        for (int d = -3; d <= 3; ++d) {
            int iy = cy0 + d, ix = cx0 + d;
            if ((unsigned)iy < 64u) Dy += __expf(-TINV * fabsf(oy - (float)iy));
            if ((unsigned)ix < 64u) Dx += __expf(-TINV * fabsf(ox - (float)ix));
        }
        params[(b << 12) + j] = make_float4(oy, ox, 1.f / Dy, 1.f / Dx);
    }

    // loads: wave w covers channels 8w..8w+7, 64-wide coalesced
    #pragma unroll
    for (int k = 0; k < 8; ++k) {
        int c = wN * 8 + k;
        tile[c][jj] = x[((size_t)(b * NC + c) << 12) + j0 + jj];
    }
    __syncthreads();

    // write: thread (j2 = t>>2, q = t&3) -> pairs 4q..4q+3 of source j0+j2
    // as ONE uint4 (16 B) -> fully coalesced; pairing identical to baseline.
    {
        int j2 = t >> 2, q = t & 3;
        int c0 = q << 3;             // first channel of this quad
        uint4 o;
        o.x = h2_as_u32(__floats2half2_rn(tile[c0 + 0][j2], tile[c0 + 1][j2]));
        o.y = h2_as_u32(__floats2half2_rn(tile[c0 + 2][j2], tile[c0 + 3][j2]));
        o.z = h2_as_u32(__floats2half2_rn(tile[c0 + 4][j2], tile[c0 + 5][j2]));
        o.w = h2_as_u32(__floats2half2_rn(tile[c0 + 6][j2], tile[c0 + 7][j2]));
        *(uint4*)&xt2u[((size_t)((b << 12) + j0 + j2) << 4) + (q << 2)] = o;
    }
}

// grid: (64 tiles, 8 batches); ALL 32 channels per block
__global__ __launch_bounds__(256) void gather_kernel(
    const float4* __restrict__ params, const unsigned int* __restrict__ xtu,
    float* __restrict__ out)
{
    // pool layout (u32): wp 4*MAXS*4 | sj 4*MAXS | XS 4 waves * 2 bufs * 512
    __shared__ __align__(16) unsigned int pool[4 * MAXS * 4 + 4 * MAXS + 4096];

    const int b    = blockIdx.y;
    const int tile = blockIdx.x;
    const int ty0  = (tile >> 3) << 3;
    const int tx0  = (tile & 7) << 3;

    const int tid  = threadIdx.x;
    const int lane = tid & 63;
    const int wv   = __builtin_amdgcn_readfirstlane(tid >> 6);

    float4*       wpW = ((float4*)pool) + wv * MAXS;
    int*          sjW = ((int*)pool) + 4 * MAXS * 4 + wv * MAXS;
    unsigned int* XSW = pool + 4 * MAXS * 4 + 4 * MAXS + wv * 1024;

    const float iy = (float)(ty0 + (lane >> 3));
    const float ix = (float)(tx0 + (lane & 7));

    __half2 acc16[16];
    #pragma unroll
    for (int c = 0; c < 16; ++c) acc16[c] = __floats2half2_rn(0.f, 0.f);

    const float4*       pb = params + (b << 12);
    const unsigned int* xb = xtu + ((size_t)(b << 12) << 4);  // 16 u32 per src

    const int srow = lane >> 5;           // 2 window rows x 32 cols per round
    const int scol = lane & 31;

    // ---- screen: all 3 rounds' param loads issued together ----
    float4 pr3[3]; int jr3[3]; bool va3[3];
    #pragma unroll
    for (int r = 0; r < 3; ++r) {
        int ry = wv + srow * 4 + r * 8;   // all 24 rows over 4 waves
        int jy = ty0 - RWIN + ry;
        int jx = tx0 - RWIN + scol;
        bool valid = ((unsigned)jy < 64u) && ((unsigned)jx < 64u) && (scol < WDIM);
        int j = (jy << 6) + jx;
        va3[r] = valid; jr3[r] = j;
        pr3[r] = pb[valid ? j : 0];
    }

    // ---- compact into one per-wave survivor list ----
    int total = 0;
    #pragma unroll
    for (int r = 0; r < 3; ++r) {
        float4 p = pr3[r];
        float cy = fminf(fmaxf(p.x, 0.f), 63.f);
        float cx = fminf(fmaxf(p.y, 0.f), 63.f);
        float dyr = fmaxf(fmaxf((float)ty0 - cy, cy - ((float)ty0 + 7.f)), 0.f);
        float dxr = fmaxf(fmaxf((float)tx0 - cx, cx - ((float)tx0 + 7.f)), 0.f);
        bool pred = va3[r] && (dyr + dxr < RCUT);
        unsigned long long m = __ballot(pred);
        if (pred) {
            int pos = total + __builtin_amdgcn_mbcnt_hi((unsigned)(m >> 32),
                              __builtin_amdgcn_mbcnt_lo((unsigned)m, 0u));
            wpW[pos] = p;
            sjW[pos] = jr3[r];
        }
        total += __popcll(m);
    }
    // zero-weight dummy pads odd totals: p.z==0 -> g==0 exactly; x finite
    if ((total & 1) && lane == 0) {
        wpW[total] = make_float4(1.f, 1.f, 0.f, 0.f);
        sjW[total] = sjW[0];
    }
    const int padT = total + (total & 1);
    const int nch  = (padT + 31) >> 5;

    // ---- staging helpers: 2 lanes x 32 B per survivor, 32 surv/chunk ----
    auto stage_load = [&](int c, uint4& A, uint4& B) {
        int s = (c << 5) + (lane >> 1);
        A = make_uint4(0u, 0u, 0u, 0u); B = A;
        if (s < padT) {
            const unsigned int* src = xb + (size_t)sjW[s] * 16 + ((lane & 1) << 3);
            A = *(const uint4*)src;
            B = *(const uint4*)(src + 4);
        }
    };
    auto stage_write = [&](int c, uint4 A, uint4 B) {
        unsigned int* d = XSW + ((c & 1) << 9) + (lane << 3);
        *(uint4*)d       = A;
        *(uint4*)(d + 4) = B;
    };

    // ---- pipelined FMA: load c+1 -> FMA c (LDS broadcast) -> write c+1 ----
    if (nch > 0) {
        uint4 a0, b0;
        stage_load(0, a0, b0);
        stage_write(0, a0, b0);
        for (int c = 0; c < nch; ++c) {
            uint4 na, nb;
            const bool more = (c + 1) < nch;
            if (more) stage_load(c + 1, na, nb);

            int cnt_c = min(32, padT - (c << 5));
            const uint4* XR = (const uint4*)(XSW + ((c & 1) << 9));
            for (int k = 0; k < cnt_c; k += 2) {
                float4 p0 = wpW[(c << 5) + k], p1 = wpW[(c << 5) + k + 1];
                const uint4* x0 = XR + (k << 2);
                const uint4* x1 = XR + ((k + 1) << 2);
                uint4 A[4], Bv[4];
                #pragma unroll
                for (int q = 0; q < 4; ++q) { A[q] = x0[q]; Bv[q] = x1[q]; }

                // per-dim normalize before product (fp32 overflow safety)
                float g0 = (__expf(-TINV * fabsf(p0.x - iy)) * p0.z)
                         * (__expf(-TINV * fabsf(p0.y - ix)) * p0.w);
                float g1 = (__expf(-TINV * fabsf(p1.x - iy)) * p1.z)
                         * (__expf(-TINV * fabsf(p1.y - ix)) * p1.w);
                __half2 hg0 = __float2half2_rn(g0);
                __half2 hg1 = __float2half2_rn(g1);

                #pragma unroll
                for (int q = 0; q < 4; ++q) {
                    acc16[4 * q + 0] = __hfma2(hg0, u32_as_h2(A[q].x), acc16[4 * q + 0]);
                    acc16[4 * q + 1] = __hfma2(hg0, u32_as_h2(A[q].y), acc16[4 * q + 1]);
                    acc16[4 * q + 2] = __hfma2(hg0, u32_as_h2(A[q].z), acc16[4 * q + 2]);
                    acc16[4 * q + 3] = __hfma2(hg0, u32_as_h2(A[q].w), acc16[4 * q + 3]);
                }
                #pragma unroll
                for (int q = 0; q < 4; ++q) {
                    acc16[4 * q + 0] = __hfma2(hg1, u32_as_h2(Bv[q].x), acc16[4 * q + 0]);
                    acc16[4 * q + 1] = __hfma2(hg1, u32_as_h2(Bv[q].y), acc16[4 * q + 1]);
                    acc16[4 * q + 2] = __hfma2(hg1, u32_as_h2(Bv[q].z), acc16[4 * q + 2]);
                    acc16[4 * q + 3] = __hfma2(hg1, u32_as_h2(Bv[q].w), acc16[4 * q + 3]);
                }
            }
            if (more) stage_write(c + 1, na, nb);
        }
    }

    // ---- cross-wave reduction, PACKED half2; redu overlays pool after
    //      barrier; stride 17 u32 (odd) -> conflict-free ----
    __syncthreads();
    unsigned int* redu = pool;
    unsigned int* myr  = redu + (unsigned)tid * 17;
    #pragma unroll
    for (int c = 0; c < 16; ++c) myr[c] = h2_as_u32(acc16[c]);
    __syncthreads();

    int t  = tid & 63;                    // target within tile
    int c0 = tid >> 6;                    // base ch-pair 0..3
    #pragma unroll
    for (int k = 0; k < 4; ++k) {
        int c2 = c0 + (k << 2);           // ch-pair 0..15
        float sx = 0.f, sy = 0.f;
        #pragma unroll
        for (int w = 0; w < 4; ++w) {
            float2 f = __half22float2(u32_as_h2(redu[(unsigned)((w << 6) + t) * 17 + c2]));
            sx += f.x; sy += f.y;
        }
        int ch   = c2 << 1;
        int base = (((b << 5) + ch) << 12) + (ty0 + (t >> 3)) * 64 + (tx0 + (t & 7));
        out[base]      = sx;
        out[base + HW] = sy;
    }
}

extern "C" void kernel_launch(void* const* d_in, const int* in_sizes, int n_in,
                              void* d_out, int out_size, void* d_ws, size_t ws_size,
                              hipStream_t stream) {
    const float* x  = (const float*)d_in[0];   // [8,32,64,64]
    const float* of = (const float*)d_in[1];   // [8,2,64,64]
    float* out = (float*)d_out;                // [8,32,64,64] fp32

    float4*       params = (float4*)d_ws;                                      // 512 KB
    unsigned int* xt2u   = (unsigned int*)((char*)d_ws + NB * HW * sizeof(float4)); // 2 MB

    prep_kernel<<<dim3(NB * 64), dim3(256), 0, stream>>>(x, of, params, xt2u);
    gather_kernel<<<dim3(64, NB), dim3(256), 0, stream>>>(
        params, xt2u, out);
}

// Round 7
// 65.335 us; speedup vs baseline: 1.1245x; 1.0027x over previous
//
#include <hip/hip_runtime.h>
#include <hip/hip_fp16.h>
#include <math.h>

#define HW    4096
#define NC    32
#define NB    8
#define TINV  10.0f            // 1/TEMP
#define RWIN  8                // window radius; missed sources need |of|>5.5
#define WDIM  (8 + 2 * RWIN)   // 24
#define RCUT  1.2f             // rect cut; boundary weight e^-12 ~ 6e-6 rel
#define MAXS  76               // per-wave cap: 3 rows x 24 cols = 72 + pad

// v7: 8-wave gather (512 thr): balanced 3-rows-per-wave screen halves the
// per-wave serial survivor chain (~27 -> ~14) and doubles TLP (16 waves/CU).
// Lists are short -> stage-all-then-FMA (chunked dbuf degenerates at nch~1).
// Prep unchanged from v6.

__device__ __forceinline__ __half2 u32_as_h2(unsigned int u) {
    union { unsigned int u; __half2 h; } c; c.u = u; return c.h;
}
__device__ __forceinline__ unsigned int h2_as_u32(__half2 h) {
    union { __half2 h; unsigned int u; } c; c.h = h; return c.u;
}

// grid (NB*64), 256 threads: 64 j's per block, ALL 32 channels.
__global__ __launch_bounds__(256) void prep_kernel(
    const float* __restrict__ x, const float* __restrict__ of,
    float4* __restrict__ params, unsigned int* __restrict__ xt2u)
{
    __shared__ float tile[32][66];   // 8.25 KB; stride 66 -> 2-way reads (free)
    const int bx = blockIdx.x;
    const int b  = bx >> 6;
    const int j0 = (bx & 63) << 6;
    const int t  = threadIdx.x;
    const int jj = t & 63;
    const int wN = t >> 6;           // wave index 0..3

    if (t < 64) {                    // one wave computes this chunk's params
        int j = j0 + t;
        float oy = (float)(j >> 6) + of[(b * 2 + 0) * HW + j];
        float ox = (float)(j & 63) + of[(b * 2 + 1) * HW + j];
        // truncated denominators: omitted terms < e^-25 relative
        int cy0 = min(max((int)floorf(oy), 0), 63);
        int cx0 = min(max((int)floorf(ox), 0), 63);
        float Dy = 0.f, Dx = 0.f;
        #pragma unroll
        for (int d = -3; d <= 3; ++d) {
            int iy = cy0 + d, ix = cx0 + d;
            if ((unsigned)iy < 64u) Dy += __expf(-TINV * fabsf(oy - (float)iy));
            if ((unsigned)ix < 64u) Dx += __expf(-TINV * fabsf(ox - (float)ix));
        }
        params[(b << 12) + j] = make_float4(oy, ox, 1.f / Dy, 1.f / Dx);
    }

    // loads: wave w covers channels 8w..8w+7, 64-wide coalesced
    #pragma unroll
    for (int k = 0; k < 8; ++k) {
        int c = wN * 8 + k;
        tile[c][jj] = x[((size_t)(b * NC + c) << 12) + j0 + jj];
    }
    __syncthreads();

    // write: thread (j2 = t>>2, q = t&3) -> pairs 4q..4q+3 of source j0+j2
    // as ONE uint4 (16 B) -> fully coalesced; pairing identical to baseline.
    {
        int j2 = t >> 2, q = t & 3;
        int c0 = q << 3;             // first channel of this quad
        uint4 o;
        o.x = h2_as_u32(__floats2half2_rn(tile[c0 + 0][j2], tile[c0 + 1][j2]));
        o.y = h2_as_u32(__floats2half2_rn(tile[c0 + 2][j2], tile[c0 + 3][j2]));
        o.z = h2_as_u32(__floats2half2_rn(tile[c0 + 4][j2], tile[c0 + 5][j2]));
        o.w = h2_as_u32(__floats2half2_rn(tile[c0 + 6][j2], tile[c0 + 7][j2]));
        *(uint4*)&xt2u[((size_t)((b << 12) + j0 + j2) << 4) + (q << 2)] = o;
    }
}

// grid: (64 tiles, 8 batches); 512 threads = 8 waves; 32 channels per block
__global__ __launch_bounds__(512, 4) void gather_kernel(
    const float4* __restrict__ params, const unsigned int* __restrict__ xtu,
    float* __restrict__ out)
{
    // pool u32 layout: wp 8*MAXS*4 (2432) | sj 8*MAXS (608) | XS 8*MAXS*16 (9728)
    // total 12768 u32 = 51 KB; redu overlay needs 512*17 = 8704 u32 (fits).
    __shared__ __align__(16) unsigned int pool[12768];

    const int b    = blockIdx.y;
    const int tile = blockIdx.x;
    const int ty0  = (tile >> 3) << 3;
    const int tx0  = (tile & 7) << 3;

    const int tid  = threadIdx.x;
    const int lane = tid & 63;
    const int wv   = __builtin_amdgcn_readfirstlane(tid >> 6);  // 0..7

    float4*       wpW = ((float4*)pool) + wv * MAXS;
    int*          sjW = ((int*)pool) + 8 * MAXS * 4 + wv * MAXS;
    unsigned int* XSW = pool + 8 * MAXS * 4 + 8 * MAXS + wv * (MAXS * 16);

    const float iy = (float)(ty0 + (lane >> 3));
    const float ix = (float)(tx0 + (lane & 7));

    __half2 acc16[16];
    #pragma unroll
    for (int c = 0; c < 16; ++c) acc16[c] = __floats2half2_rn(0.f, 0.f);

    const float4*       pb = params + (b << 12);
    const unsigned int* xb = xtu + ((size_t)(b << 12) << 4);  // 16 u32 per src

    // ---- screen: wave wv covers window-rows {wv, wv+8, wv+16}; all 3
    //      param loads issued upfront (one exposed latency) ----
    float4 pr3[3]; int jr3[3]; bool va3[3];
    #pragma unroll
    for (int r = 0; r < 3; ++r) {
        int ry = wv + (r << 3);
        int jy = ty0 - RWIN + ry;
        int jx = tx0 - RWIN + lane;
        bool valid = ((unsigned)jy < 64u) && ((unsigned)jx < 64u) && (lane < WDIM);
        int j = (jy << 6) + jx;
        va3[r] = valid; jr3[r] = j;
        pr3[r] = pb[valid ? j : 0];
    }

    // ---- compact into one per-wave survivor list ----
    int total = 0;
    #pragma unroll
    for (int r = 0; r < 3; ++r) {
        float4 p = pr3[r];
        float cy = fminf(fmaxf(p.x, 0.f), 63.f);
        float cx = fminf(fmaxf(p.y, 0.f), 63.f);
        float dyr = fmaxf(fmaxf((float)ty0 - cy, cy - ((float)ty0 + 7.f)), 0.f);
        float dxr = fmaxf(fmaxf((float)tx0 - cx, cx - ((float)tx0 + 7.f)), 0.f);
        bool pred = va3[r] && (dyr + dxr < RCUT);
        unsigned long long m = __ballot(pred);
        if (pred) {
            int pos = total + __builtin_amdgcn_mbcnt_hi((unsigned)(m >> 32),
                              __builtin_amdgcn_mbcnt_lo((unsigned)m, 0u));
            wpW[pos] = p;
            sjW[pos] = jr3[r];
        }
        total += __popcll(m);
    }
    // zero-weight dummy pads odd totals: p.z==0 -> g==0 exactly; x finite
    if ((total & 1) && lane == 0) {
        wpW[total] = make_float4(1.f, 1.f, 0.f, 0.f);
        sjW[total] = sjW[0];
    }
    const int padT = total + (total & 1);

    // ---- stage ALL survivors: 2 lanes x 32 B per survivor, 32/pass ----
    for (int m0 = 0; m0 < padT; m0 += 32) {
        int s = m0 + (lane >> 1);
        if (s < padT) {
            const unsigned int* src = xb + (size_t)sjW[s] * 16 + ((lane & 1) << 3);
            uint4 A = *(const uint4*)src;
            uint4 B = *(const uint4*)(src + 4);
            unsigned int* d = XSW + (s << 4) + ((lane & 1) << 3);
            *(uint4*)d       = A;
            *(uint4*)(d + 4) = B;
        }
    }

    // ---- FMA over survivors, 2-wide, packed fp16, LDS broadcast reads ----
    for (int k = 0; k < padT; k += 2) {
        float4 p0 = wpW[k], p1 = wpW[k + 1];
        const uint4* x0 = (const uint4*)(XSW + (k << 4));
        const uint4* x1 = (const uint4*)(XSW + ((k + 1) << 4));
        uint4 A[4], Bv[4];
        #pragma unroll
        for (int q = 0; q < 4; ++q) { A[q] = x0[q]; Bv[q] = x1[q]; }

        // per-dim normalize before product (fp32 overflow safety)
        float g0 = (__expf(-TINV * fabsf(p0.x - iy)) * p0.z)
                 * (__expf(-TINV * fabsf(p0.y - ix)) * p0.w);
        float g1 = (__expf(-TINV * fabsf(p1.x - iy)) * p1.z)
                 * (__expf(-TINV * fabsf(p1.y - ix)) * p1.w);
        __half2 hg0 = __float2half2_rn(g0);
        __half2 hg1 = __float2half2_rn(g1);

        #pragma unroll
        for (int q = 0; q < 4; ++q) {
            acc16[4 * q + 0] = __hfma2(hg0, u32_as_h2(A[q].x), acc16[4 * q + 0]);
            acc16[4 * q + 1] = __hfma2(hg0, u32_as_h2(A[q].y), acc16[4 * q + 1]);
            acc16[4 * q + 2] = __hfma2(hg0, u32_as_h2(A[q].z), acc16[4 * q + 2]);
            acc16[4 * q + 3] = __hfma2(hg0, u32_as_h2(A[q].w), acc16[4 * q + 3]);
        }
        #pragma unroll
        for (int q = 0; q < 4; ++q) {
            acc16[4 * q + 0] = __hfma2(hg1, u32_as_h2(Bv[q].x), acc16[4 * q + 0]);
            acc16[4 * q + 1] = __hfma2(hg1, u32_as_h2(Bv[q].y), acc16[4 * q + 1]);
            acc16[4 * q + 2] = __hfma2(hg1, u32_as_h2(Bv[q].z), acc16[4 * q + 2]);
            acc16[4 * q + 3] = __hfma2(hg1, u32_as_h2(Bv[q].w), acc16[4 * q + 3]);
        }
    }

    // ---- cross-wave reduction (8-way), PACKED half2; redu overlays pool
    //      after barrier; stride 17 u32 (odd) -> conflict-free ----
    __syncthreads();
    unsigned int* redu = pool;
    unsigned int* myr  = redu + (unsigned)tid * 17;
    #pragma unroll
    for (int c = 0; c < 16; ++c) myr[c] = h2_as_u32(acc16[c]);
    __syncthreads();

    int t  = tid & 63;                    // target within tile
    int c0 = tid >> 6;                    // base ch-pair 0..7
    #pragma unroll
    for (int k = 0; k < 2; ++k) {
        int c2 = c0 + (k << 3);           // ch-pair 0..15
        float sx = 0.f, sy = 0.f;
        #pragma unroll
        for (int w = 0; w < 8; ++w) {
            float2 f = __half22float2(u32_as_h2(redu[(unsigned)((w << 6) + t) * 17 + c2]));
            sx += f.x; sy += f.y;
        }
        int ch   = c2 << 1;
        int base = (((b << 5) + ch) << 12) + (ty0 + (t >> 3)) * 64 + (tx0 + (t & 7));
        out[base]      = sx;
        out[base + HW] = sy;
    }
}

extern "C" void kernel_launch(void* const* d_in, const int* in_sizes, int n_in,
                              void* d_out, int out_size, void* d_ws, size_t ws_size,
                              hipStream_t stream) {
    const float* x  = (const float*)d_in[0];   // [8,32,64,64]
    const float* of = (const float*)d_in[1];   // [8,2,64,64]
    float* out = (float*)d_out;                // [8,32,64,64] fp32

    float4*       params = (float4*)d_ws;                                      // 512 KB
    unsigned int* xt2u   = (unsigned int*)((char*)d_ws + NB * HW * sizeof(float4)); // 2 MB

    prep_kernel<<<dim3(NB * 64), dim3(256), 0, stream>>>(x, of, params, xt2u);
    gather_kernel<<<dim3(64, NB), dim3(512), 0, stream>>>(
        params, xt2u, out);
}